// Round 1
// baseline (212.049 us; speedup 1.0000x reference)
//
#include <hip/hip_runtime.h>
#include <hip/hip_bf16.h>

typedef _Float16 half8 __attribute__((ext_vector_type(8)));
typedef _Float16 half4 __attribute__((ext_vector_type(4)));
typedef float floatx4 __attribute__((ext_vector_type(4)));
// 4-byte-aligned float4: image row bases are only 4B aligned ((..)*3 floats)
typedef float f4u __attribute__((ext_vector_type(4), aligned(4)));

#define PD 768   // projection dim (N)
#define KE 768   // effective K after mask-folding (16*16*3)
#define NB 64    // batch
#define GP 14    // grid size (224/16)

// ---------------------------------------------------------------------------
// Kernel 1: fold the 4 masked channel-groups into per-class effective weights.
// Classes: rh,rw in {0: g==0, 1: 1..12, 2: g==13}; cls = rh*3+rw.
// Output TRANSPOSED: Weff[cls][d][kk], kk = (ph*16+pw)*3+cc contiguous,
// so the GEMM's B-tile staging reads k-contiguous f16.
// ---------------------------------------------------------------------------
__global__ __launch_bounds__(256) void prep_weights(
    const float* __restrict__ W, _Float16* __restrict__ Weff) {
  const int d = blockIdx.x;
  for (int kk = threadIdx.x; kk < KE; kk += 256) {
    int pix = kk / 3;
    int cc  = kk - pix * 3;
    int ph = pix >> 4, pw = pix & 15;
    const float* base = W + (size_t)(pix * 15 + cc) * PD + d;
    float w0 = base[0];          // original image channels
    float w1 = base[3  * PD];    // (oh=0, ow=0): h<216 && w<216
    float w2 = base[6  * PD];    // (oh=8, ow=0): h>=8  && w<216
    float w3 = base[9  * PD];    // (oh=0, ow=8): h<216 && w>=8
    float w4 = base[12 * PD];    // (oh=8, ow=8): h>=8  && w>=8
    float hlt[3] = {1.f, 1.f, (ph < 8) ? 1.f : 0.f};   // h<216 per rh
    float hge[3] = {(ph >= 8) ? 1.f : 0.f, 1.f, 1.f};  // h>=8  per rh
    float wlt[3] = {1.f, 1.f, (pw < 8) ? 1.f : 0.f};
    float wge[3] = {(pw >= 8) ? 1.f : 0.f, 1.f, 1.f};
#pragma unroll
    for (int rh = 0; rh < 3; ++rh)
#pragma unroll
      for (int rw = 0; rw < 3; ++rw) {
        float v = w0 + hlt[rh] * wlt[rw] * w1 + hge[rh] * wlt[rw] * w2
                     + hlt[rh] * wge[rw] * w3 + hge[rh] * wge[rw] * w4;
        Weff[((size_t)(rh * 3 + rw) * PD + d) * KE + kk] = (_Float16)v;
      }
  }
}

// ---------------------------------------------------------------------------
// Kernel 2: class-grouped GEMM. out[b,p,:] = patch3(b,p) @ Weff[cls] + bias.
// BM=BN=128, BK=96 (2 image pixel-rows = 2x48 contiguous floats per A row).
// 256 threads = 4 waves in 2x2; each wave owns 64x64 (4x4 frags of 16x16).
// ---------------------------------------------------------------------------
#define BM 128
#define BN 128
#define BK 96
#define LP 104   // padded LDS row in f16: 52 words, 52%32=20 -> <=2-way (free)

__global__ __launch_bounds__(256) void spt_gemm(
    const float* __restrict__ img, const _Float16* __restrict__ Weff,
    const float* __restrict__ bias, float* __restrict__ out) {
  __shared__ _Float16 Al[BM * LP];
  __shared__ _Float16 Bl[BN * LP];

  const int t  = threadIdx.x;
  const int bt = blockIdx.x / 6;   // m-tile global index (100 total)
  const int nt = blockIdx.x % 6;   // n-tile (768/128)

  // class decode: tiles_m per cls = {1,6,1,6,72,6,1,6,1}; cum = {0,1,7,8,14,86,92,93,99}
  int cls, mt;
  if      (bt < 1)  { cls = 0; mt = bt; }
  else if (bt < 7)  { cls = 1; mt = bt - 1; }
  else if (bt < 8)  { cls = 2; mt = bt - 7; }
  else if (bt < 14) { cls = 3; mt = bt - 8; }
  else if (bt < 86) { cls = 4; mt = bt - 14; }
  else if (bt < 92) { cls = 5; mt = bt - 86; }
  else if (bt < 93) { cls = 6; mt = bt - 92; }
  else if (bt < 99) { cls = 7; mt = bt - 93; }
  else              { cls = 8; mt = bt - 99; }

  const int rh  = cls / 3, rw = cls % 3;
  const int gh0 = (rh == 0) ? 0 : (rh == 1 ? 1 : 13);
  const int nh  = (rh == 1) ? 12 : 1;
  const int gw0 = (rw == 0) ? 0 : (rw == 1 ? 1 : 13);
  const int nw  = (rw == 1) ? 12 : 1;
  const int per = nh * nw;
  const int Mc  = NB * per;

  // ---- A staging address precompute: 3072 float4-chunks, 12 per thread ----
  int  a_gbase[12], a_ldso[12];
  bool a_valid[12];
#pragma unroll
  for (int i = 0; i < 12; ++i) {
    int c   = i * 256 + t;       // chunk id
    int row = c / 24;            // 24 chunks (96 floats) per A row
    int q   = c - row * 24;
    int seg = q / 12;            // which of the 2 pixel-rows in this K-step
    int off = q - seg * 12;      // float4 within the 48-float segment
    int R   = mt * BM + row;
    bool v  = R < Mc;
    int Rc  = v ? R : 0;
    int b   = Rc / per;
    int rem = Rc - b * per;
    int ih  = rem / nw;
    int iw  = rem - ih * nw;
    int gh  = gh0 + ih, gw = gw0 + iw;
    a_gbase[i] = ((b * 224 + gh * 16 + seg) * 224 + gw * 16) * 3 + off * 4;
    a_ldso[i]  = row * LP + seg * 48 + off * 4;
    a_valid[i] = v;
  }
  // ---- B staging precompute: 1536 16B-chunks, 6 per thread ----
  int b_goff[6], b_ldso[6];
#pragma unroll
  for (int i = 0; i < 6; ++i) {
    int c   = i * 256 + t;
    int dd  = c / 12;            // 12 chunks (96 f16) per B row
    int off = c - dd * 12;
    b_goff[i] = ((size_t)0 + cls * PD + nt * BN + dd) * KE + off * 8;
    b_ldso[i] = dd * LP + off * 8;
  }

  const int lane = t & 63;
  const int wave = t >> 6;
  const int wr = wave >> 1, wc = wave & 1;
  const int lrow = lane & 15;
  const int lk   = (lane >> 4) * 8;

  floatx4 acc[4][4];
#pragma unroll
  for (int m = 0; m < 4; ++m)
#pragma unroll
    for (int n = 0; n < 4; ++n) acc[m][n] = (floatx4)0.f;

  for (int ks = 0; ks < 8; ++ks) {   // K = 768 = 8 * 96
    __syncthreads();
    // stage A: fp32 -> f16 convert; each K-step advances 2 image rows
#pragma unroll
    for (int i = 0; i < 12; ++i) {
      f4u vv = a_valid[i] ? *(const f4u*)(img + a_gbase[i] + ks * 1344)
                          : (f4u)0.f;
      half4 h;
      h.x = (_Float16)vv.x; h.y = (_Float16)vv.y;
      h.z = (_Float16)vv.z; h.w = (_Float16)vv.w;
      *(half4*)(Al + a_ldso[i]) = h;
    }
    // stage B: already f16, k-contiguous copy
#pragma unroll
    for (int i = 0; i < 6; ++i)
      *(half8*)(Bl + b_ldso[i]) = *(const half8*)(Weff + b_goff[i] + ks * 96);
    __syncthreads();
    // compute: 3 k-frags x 4x4 MFMA
#pragma unroll
    for (int kf = 0; kf < 3; ++kf) {
      half8 af[4], bf[4];
#pragma unroll
      for (int m = 0; m < 4; ++m)
        af[m] = *(const half8*)(Al + (wr * 64 + m * 16 + lrow) * LP + kf * 32 + lk);
#pragma unroll
      for (int n = 0; n < 4; ++n)
        bf[n] = *(const half8*)(Bl + (wc * 64 + n * 16 + lrow) * LP + kf * 32 + lk);
#pragma unroll
      for (int m = 0; m < 4; ++m)
#pragma unroll
        for (int n = 0; n < 4; ++n)
          acc[m][n] = __builtin_amdgcn_mfma_f32_16x16x32_f16(af[m], bf[n],
                                                             acc[m][n], 0, 0, 0);
    }
  }

  // epilogue: bias add + scatter rows back to (b, gh*14+gw)
  const int col = nt * BN + wc * 64 + lrow;   // C/D: col = lane&15
  float bv[4];
#pragma unroll
  for (int n = 0; n < 4; ++n) bv[n] = bias[col + n * 16];
  const int rquad = (lane >> 4) * 4;          // C/D: row = (lane>>4)*4 + reg
#pragma unroll
  for (int m = 0; m < 4; ++m) {
#pragma unroll
    for (int j = 0; j < 4; ++j) {
      int R = mt * BM + wr * 64 + m * 16 + rquad + j;
      if (R < Mc) {
        int b   = R / per;
        int rem = R - b * per;
        int ih  = rem / nw;
        int iw  = rem - ih * nw;
        int p   = (gh0 + ih) * GP + (gw0 + iw);
        float* orow = out + ((size_t)b * 196 + p) * PD + col;
#pragma unroll
        for (int n = 0; n < 4; ++n)
          orow[n * 16] = acc[m][n][j] + bv[n];
      }
    }
  }
}

extern "C" void kernel_launch(void* const* d_in, const int* in_sizes, int n_in,
                              void* d_out, int out_size, void* d_ws, size_t ws_size,
                              hipStream_t stream) {
  const float* img  = (const float*)d_in[0];   // (64,224,224,3) fp32
  const float* W    = (const float*)d_in[1];   // (3840,768) fp32
  const float* bias = (const float*)d_in[2];   // (768,) fp32
  float* out = (float*)d_out;                  // (64,196,768) fp32
  _Float16* Weff = (_Float16*)d_ws;            // 9*768*768 f16 = 10.1 MB

  prep_weights<<<768, 256, 0, stream>>>(W, Weff);
  // blocks: 100 m-tiles (1+6+1+6+72+6+1+6+1) x 6 n-tiles
  spt_gemm<<<600, 256, 0, stream>>>(img, Weff, bias, out);
}

// Round 5
// 137.131 us; speedup vs baseline: 1.5463x; 1.5463x over previous
//
#include <hip/hip_runtime.h>
#include <hip/hip_bf16.h>

typedef _Float16 half8 __attribute__((ext_vector_type(8)));
typedef _Float16 half4 __attribute__((ext_vector_type(4)));
typedef float floatx4 __attribute__((ext_vector_type(4)));

#define PD 768   // projection dim (N)
#define KE 768   // effective K (16*16*3)
#define NB 64

// class row-bases (rows grouped by class; all class sizes are multiples of 64)
__device__ __forceinline__ int cls_row_base(int cls) {
  return (cls == 0) ? 0 : (cls == 1) ? 64 : (cls == 2) ? 832 : (cls == 3) ? 896
       : (cls == 4) ? 1664 : (cls == 5) ? 10880 : (cls == 6) ? 11648
       : (cls == 7) ? 11712 : 12480;
}

__device__ __forceinline__ void gl_lds16(const _Float16* g, _Float16* l) {
  __builtin_amdgcn_global_load_lds(
      (const __attribute__((address_space(1))) unsigned int*)g,
      (__attribute__((address_space(3))) unsigned int*)l, 16, 0, 0);
}

// ---------------------------------------------------------------------------
// Kernel 1: fold masked channel-groups into 9 per-class weights, f16,
// layout Weff[cls][d][kk] (k-contiguous). Coalesced: block stages 240
// CONSECUTIVE W rows (16 pixels x 15 ch) x 64 d into LDS, then transposes.
// ---------------------------------------------------------------------------
__global__ __launch_bounds__(256) void prep_weights(
    const float* __restrict__ W, _Float16* __restrict__ Weff) {
  __shared__ float Wl[240][68];   // stride 68: 16B-aligned float4 rows
  const int t  = threadIdx.x;
  const int ck = blockIdx.x & 15;   // kk-chunk (48 kk = 16 pixels)
  const int cd = blockIdx.x >> 4;   // d-chunk (64)
  const int p0 = ck * 16;
  const int d0 = cd * 64;
#pragma unroll
  for (int i = 0; i < 15; ++i) {    // 240 rows * 16 chunks = 3840 float4
    int c = i * 256 + t;
    int row = c >> 4, off = (c & 15) * 4;
    *(floatx4*)&Wl[row][off] =
        *(const floatx4*)&W[(size_t)(p0 * 15 + row) * PD + d0 + off];
  }
  __syncthreads();
#pragma unroll
  for (int i = 0; i < 3; ++i) {     // 64 d x 12 kk-quads = 768 items
    int wi = i * 256 + t;
    int d = wi / 12, q = wi - d * 12;
    float vout[9][4];
#pragma unroll
    for (int s = 0; s < 4; ++s) {
      int kl = q * 4 + s;           // 0..47
      int pl = kl / 3, cc = kl - pl * 3;
      int pix = p0 + pl;
      int ph = pix >> 4, pw = pix & 15;
      int rb = pl * 15 + cc;
      float w0 = Wl[rb][d],     w1 = Wl[rb + 3][d], w2 = Wl[rb + 6][d],
            w3 = Wl[rb + 9][d], w4 = Wl[rb + 12][d];
      float hlt[3] = {1.f, 1.f, (ph < 8) ? 1.f : 0.f};
      float hge[3] = {(ph >= 8) ? 1.f : 0.f, 1.f, 1.f};
      float wlt[3] = {1.f, 1.f, (pw < 8) ? 1.f : 0.f};
      float wge[3] = {(pw >= 8) ? 1.f : 0.f, 1.f, 1.f};
#pragma unroll
      for (int rh = 0; rh < 3; ++rh)
#pragma unroll
        for (int rw = 0; rw < 3; ++rw)
          vout[rh * 3 + rw][s] = w0 + hlt[rh] * wlt[rw] * w1
              + hge[rh] * wlt[rw] * w2 + hlt[rh] * wge[rw] * w3
              + hge[rh] * wge[rw] * w4;
    }
#pragma unroll
    for (int cls = 0; cls < 9; ++cls) {
      half4 h;
      h.x = (_Float16)vout[cls][0]; h.y = (_Float16)vout[cls][1];
      h.z = (_Float16)vout[cls][2]; h.w = (_Float16)vout[cls][3];
      *(half4*)&Weff[((size_t)cls * PD + d0 + d) * KE + ck * 48 + q * 4] = h;
    }
  }
}

// ---------------------------------------------------------------------------
// Kernel 2: im2col + f32->f16: A[12544][768], rows class-grouped so the GEMM
// stages linear row blocks. Each item = 8 consecutive floats of an image row.
// ---------------------------------------------------------------------------
__global__ __launch_bounds__(256) void prep_imcol(
    const float* __restrict__ img, _Float16* __restrict__ Ap) {
  const int total = NB * 224 * 84;          // 1,204,224 8-float items
  for (int id = blockIdx.x * 256 + threadIdx.x; id < total; id += 2048 * 256) {
    int b   = id / 18816;
    int rem = id - b * 18816;
    int h   = rem / 84;
    int c8  = rem - h * 84;
    int gw  = c8 / 6;
    int j8  = c8 - gw * 6;
    int gh  = h >> 4, ph = h & 15;
    int rh  = (gh == 0) ? 0 : ((gh >= 13) ? 2 : 1);
    int rw  = (gw == 0) ? 0 : ((gw >= 13) ? 2 : 1);
    int gh0 = (rh == 1) ? 1 : ((rh == 2) ? 13 : 0);
    int gw0 = (rw == 1) ? 1 : ((rw == 2) ? 13 : 0);
    int nh  = (rh == 1) ? 12 : 1;
    int nw  = (rw == 1) ? 12 : 1;
    int cls = rh * 3 + rw;
    int r   = cls_row_base(cls) + (b * nh + (gh - gh0)) * nw + (gw - gw0);
    const float* src = img + (size_t)(b * 224 + h) * 672 + c8 * 8;
    floatx4 v0 = *(const floatx4*)src;
    floatx4 v1 = *(const floatx4*)(src + 4);
    half8 o;
    o[0] = (_Float16)v0.x; o[1] = (_Float16)v0.y;
    o[2] = (_Float16)v0.z; o[3] = (_Float16)v0.w;
    o[4] = (_Float16)v1.x; o[5] = (_Float16)v1.y;
    o[6] = (_Float16)v1.z; o[7] = (_Float16)v1.w;
    *(half8*)&Ap[(size_t)r * KE + ph * 48 + j8 * 8] = o;
  }
}

// ---------------------------------------------------------------------------
// Kernel 3: class-grouped GEMM, BM=64 BN=128 BK=64, 4 waves (each 32x64),
// global_load_lds(16B) both operands, XOR-swizzled LDS, 2-phase dbuf prefetch.
// ---------------------------------------------------------------------------
__global__ __launch_bounds__(256) void spt_gemm(
    const _Float16* __restrict__ Ap, const _Float16* __restrict__ Weff,
    const float* __restrict__ bias, float* __restrict__ out) {
  __shared__ _Float16 Al[2][64 * 64];     // 8 KB per buffer
  __shared__ _Float16 Bl[2][128 * 64];    // 16 KB per buffer

  const int t  = threadIdx.x;
  const int nt = blockIdx.x % 6;
  const int bt = blockIdx.x / 6;          // m-tile 0..195 (64 rows each)

  // class decode: tile counts {1,12,1,12,144,12,1,12,1}
  int cls;
  if      (bt < 1)   cls = 0;
  else if (bt < 13)  cls = 1;
  else if (bt < 14)  cls = 2;
  else if (bt < 26)  cls = 3;
  else if (bt < 170) cls = 4;
  else if (bt < 182) cls = 5;
  else if (bt < 183) cls = 6;
  else if (bt < 195) cls = 7;
  else               cls = 8;

  const int w = t >> 6, lane = t & 63;
  const int wr = w >> 1, wc = w & 1;
  const int lrow = lane & 15, lq = lane >> 4;

  // staging lane constants: chunk c = i*256+t -> row = i*32+(t>>3), 16B j = t&7
  const int srow = t >> 3;
  const int js = (t & 7) ^ (srow & 7);    // pre-swizzled 16B-block index
  const _Float16* Ag = Ap + (size_t)(bt * 64 + srow) * KE + js * 8;
  const _Float16* Bg = Weff + ((size_t)cls * PD + nt * 128 + srow) * KE + js * 8;

  floatx4 acc[2][4];
#pragma unroll
  for (int m = 0; m < 2; ++m)
#pragma unroll
    for (int n = 0; n < 4; ++n) acc[m][n] = (floatx4)0.f;

#define STAGE(ks, sel)                                                        \
  {                                                                           \
    _Pragma("unroll")                                                         \
    for (int i = 0; i < 2; ++i)                                               \
      gl_lds16(Ag + (size_t)i * 32 * KE + (ks) * 64,                          \
               &Al[sel][i * 2048 + w * 512]);                                 \
    _Pragma("unroll")                                                         \
    for (int i = 0; i < 4; ++i)                                               \
      gl_lds16(Bg + (size_t)i * 32 * KE + (ks) * 64,                          \
               &Bl[sel][i * 2048 + w * 512]);                                 \
  }

  int cur = 0;
  STAGE(0, 0);
  __syncthreads();
  for (int ks = 0; ks < 12; ++ks) {
    if (ks < 11) STAGE(ks + 1, cur ^ 1);
#pragma unroll
    for (int kf = 0; kf < 2; ++kf) {
      half8 af[2], bf[4];
#pragma unroll
      for (int m = 0; m < 2; ++m) {
        int row = wr * 32 + m * 16 + lrow;
        af[m] = *(const half8*)&Al[cur][row * 64
                 + ((kf * 32 + lq * 8) ^ ((row & 7) * 8))];
      }
#pragma unroll
      for (int n = 0; n < 4; ++n) {
        int row = wc * 64 + n * 16 + lrow;
        bf[n] = *(const half8*)&Bl[cur][row * 64
                 + ((kf * 32 + lq * 8) ^ ((row & 7) * 8))];
      }
#pragma unroll
      for (int m = 0; m < 2; ++m)
#pragma unroll
        for (int n = 0; n < 4; ++n)
          acc[m][n] = __builtin_amdgcn_mfma_f32_16x16x32_f16(
              af[m], bf[n], acc[m][n], 0, 0, 0);
    }
    __syncthreads();
    cur ^= 1;
  }

  // epilogue: bias + scatter class-grouped rows to (b, gh*14+gw)
  const int rh  = cls / 3, rw = cls % 3;
  const int gh0 = (rh == 1) ? 1 : ((rh == 2) ? 13 : 0);
  const int gw0 = (rw == 1) ? 1 : ((rw == 2) ? 13 : 0);
  const int nw  = (rw == 1) ? 12 : 1;
  const int nh  = (rh == 1) ? 12 : 1;
  const int per = nh * nw;
  const int cbase = cls_row_base(cls);

  const int col = nt * 128 + wc * 64 + lrow;
  float bv[4];
#pragma unroll
  for (int n = 0; n < 4; ++n) bv[n] = bias[col + n * 16];
  const int rq = lq * 4;
#pragma unroll
  for (int m = 0; m < 2; ++m) {
#pragma unroll
    for (int j = 0; j < 4; ++j) {
      int R = bt * 64 + wr * 32 + m * 16 + rq + j;
      int r = R - cbase;
      int b, ih, iw;
      if (per == 1)        { b = r; ih = 0; iw = 0; }
      else if (per == 12)  { b = r / 12; int rm = r - b * 12;
                             ih = (nw == 1) ? rm : 0; iw = (nw == 1) ? 0 : rm; }
      else                 { b = r / 144; int rm = r - b * 144;
                             ih = rm / 12; iw = rm - ih * 12; }
      int p = (gh0 + ih) * 14 + (gw0 + iw);
      float* orow = out + ((size_t)b * 196 + p) * PD + col;
#pragma unroll
      for (int n = 0; n < 4; ++n) orow[n * 16] = acc[m][n][j] + bv[n];
    }
  }
}

extern "C" void kernel_launch(void* const* d_in, const int* in_sizes, int n_in,
                              void* d_out, int out_size, void* d_ws, size_t ws_size,
                              hipStream_t stream) {
  const float* img  = (const float*)d_in[0];   // (64,224,224,3) fp32
  const float* W    = (const float*)d_in[1];   // (3840,768) fp32
  const float* bias = (const float*)d_in[2];   // (768,) fp32
  float* out = (float*)d_out;                  // (64,196,768) fp32
  _Float16* Weff = (_Float16*)d_ws;                          // 10,616,832 B
  _Float16* Ap   = (_Float16*)((char*)d_ws + 10616832);      // 19,267,584 B

  prep_weights<<<192, 256, 0, stream>>>(W, Weff);
  prep_imcol<<<2048, 256, 0, stream>>>(img, Ap);
  spt_gemm<<<196 * 6, 256, 0, stream>>>(Ap, Weff, bias, out);
}